// Round 7
// baseline (372.834 us; speedup 1.0000x reference)
//
#include <hip/hip_runtime.h>
#include <hip/hip_bf16.h>
#include <math.h>

#define SEQ 512
#define DM  256
#define NH  8

typedef __attribute__((ext_vector_type(4))) float  f32x4;
typedef __attribute__((ext_vector_type(8))) __bf16 bf16x8;
typedef __attribute__((ext_vector_type(8))) short  s16x8;

__device__ __forceinline__ short fb(float x) {
  __bf16 h = (__bf16)x;
  return __builtin_bit_cast(short, h);
}
__device__ __forceinline__ unsigned short f2bf(float f) {
  unsigned int u = __builtin_bit_cast(unsigned int, f);
  u += 0x7fffu + ((u >> 16) & 1u);
  return (unsigned short)(u >> 16);
}
__device__ __forceinline__ float bf2f(unsigned short h) {
  unsigned int u = ((unsigned int)h) << 16;
  return __builtin_bit_cast(float, u);
}
__device__ __forceinline__ s16x8 cvt8(float4 a, float4 b) {
  s16x8 o;
  o[0]=fb(a.x); o[1]=fb(a.y); o[2]=fb(a.z); o[3]=fb(a.w);
  o[4]=fb(b.x); o[5]=fb(b.y); o[6]=fb(b.z); o[7]=fb(b.w);
  return o;
}
// async global->LDS, 16B/lane; dest is wave-uniform base (+lane*16 by HW)
__device__ __forceinline__ void gll16(const void* g, void* ldsbase) {
  __builtin_amdgcn_global_load_lds((const __attribute__((address_space(1))) void*)g,
                                   (__attribute__((address_space(3))) void*)ldsbase,
                                   16, 0, 0);
}

// ---------------------------------------------------------------------------
// kconv: f32 -> bf16 streaming convert (grid*256*32 elements)
__global__ __launch_bounds__(256) void kconv(const float* __restrict__ src,
                                             unsigned short* __restrict__ dst) {
  size_t base = ((size_t)blockIdx.x * 256 + threadIdx.x) * 32;
  #pragma unroll
  for (int u = 0; u < 4; u++) {
    float4 a = *(const float4*)(src + base + u * 8);
    float4 b = *(const float4*)(src + base + u * 8 + 4);
    *(s16x8*)(dst + base + u * 8) = cvt8(a, b);
  }
}

// ---------------------------------------------------------------------------
// K0: blocks 0..31 convert k (f32->bf16); blocks 32..63 transpose v -> vT bf16
__global__ __launch_bounds__(256) void k0_convert(const float* __restrict__ kin,
                                                  const float* __restrict__ vin,
                                                  unsigned short* __restrict__ kbf,
                                                  unsigned short* __restrict__ vT) {
  __shared__ unsigned short tl[64][72];
  int b = blockIdx.x, t = threadIdx.x;
  if (b < 32) {
    int base = b * 4096 + t * 16;
    float4 a0 = *(const float4*)(kin + base);
    float4 a1 = *(const float4*)(kin + base + 4);
    float4 a2 = *(const float4*)(kin + base + 8);
    float4 a3 = *(const float4*)(kin + base + 12);
    *(s16x8*)(kbf + base)     = cvt8(a0, a1);
    *(s16x8*)(kbf + base + 8) = cvt8(a2, a3);
  } else {
    int tb = b - 32;
    int i0 = (tb >> 2) * 64;
    int m0 = (tb & 3) * 64;
    int r = t >> 2, cq = t & 3;
    #pragma unroll
    for (int u = 0; u < 4; u++) {
      float4 x = *(const float4*)(vin + (size_t)(i0 + r) * DM + m0 + cq * 16 + u * 4);
      tl[cq*16 + u*4 + 0][r] = (unsigned short)fb(x.x);
      tl[cq*16 + u*4 + 1][r] = (unsigned short)fb(x.y);
      tl[cq*16 + u*4 + 2][r] = (unsigned short)fb(x.z);
      tl[cq*16 + u*4 + 3][r] = (unsigned short)fb(x.w);
    }
    __syncthreads();
    int mm = t >> 2;
    s16x8 w0, w1;
    #pragma unroll
    for (int e = 0; e < 8; e++) { w0[e] = tl[mm][cq*16 + e]; w1[e] = tl[mm][cq*16 + 8 + e]; }
    *(s16x8*)(vT + (size_t)(m0 + mm) * SEQ + i0 + cq * 16)     = w0;
    *(s16x8*)(vT + (size_t)(m0 + mm) * SEQ + i0 + cq * 16 + 8) = w1;
  }
}

// ---------------------------------------------------------------------------
// K1: qp = q @ Wq^T  (f32 + bf16 outputs)
__global__ __launch_bounds__(256) void k1_qproj(const float* __restrict__ q,
                                                const float* __restrict__ Wq,
                                                float* __restrict__ qpf,
                                                unsigned short* __restrict__ qpb) {
  __shared__ __align__(16) float qrow[DM];
  int i = blockIdx.x, t = threadIdx.x;
  if (t < 64) *(float4*)&qrow[t*4] = *(const float4*)(q + (size_t)i * DM + t * 4);
  __syncthreads();
  int w = t >> 6, lane = t & 63;
  for (int jj = 0; jj < 64; jj++) {
    int j = w * 64 + jj;
    float4 wv = *(const float4*)(Wq + (size_t)j * DM + lane * 4);
    float s = wv.x*qrow[lane*4] + wv.y*qrow[lane*4+1] + wv.z*qrow[lane*4+2] + wv.w*qrow[lane*4+3];
    #pragma unroll
    for (int off = 32; off; off >>= 1) s += __shfl_xor(s, off);
    if (lane == 0) { qpf[(size_t)i*DM + j] = s; qpb[(size_t)i*DM + j] = f2bf(s); }
  }
}

// ---------------------------------------------------------------------------
// ka5: 2-phase pipelined per-j GEMM. Per block (head,jsplit,itile): for 4 j's,
// T_j = qpb[m0:+64] @ Wkb_j^T accumulated over 4 kt steps; per-j f32 epilogue
// acc += qpf[i,j]*T_j. B double-buffered via gll16 (issue-early, 1 barrier per
// step); A-frags loaded directly from qpb (L1/L2-hot, 16B per frag).
// Disjoint store into af8[jsplit]. grid 512, 256 thr, 64 KiB LDS, 2 blk/CU.
__global__ __launch_bounds__(256, 2) void ka5(const unsigned short* __restrict__ Wkb,
                                              const unsigned short* __restrict__ qpb,
                                              const float* __restrict__ qpf,
                                              float* __restrict__ af8) {
  __shared__ __align__(16) unsigned short lB[2][256 * 64];
  int bid = blockIdx.x;
  int head = bid & 7, rest = bid >> 3;
  int jsplit = rest >> 3, itile = rest & 7;
  int m0 = itile * 64;
  int t = threadIdx.x, w = t >> 6, lane = t & 63;
  int r = lane & 15, hi = lane >> 4;
  const int jbase = head * 32 + jsplit * 4;

  auto stage = [&](int jj, int kt, int buf) {
    const unsigned short* Bj = Wkb + (size_t)(jbase + jj) * 65536 + kt * 64;
    #pragma unroll
    for (int it = 0; it < 8; it++) {
      int chunk = w * 8 + it;
      int row = chunk * 8 + (lane >> 3);
      int cb = ((lane & 7) * 16) ^ ((row & 7) << 4);   // inverse-swz source
      gll16((const char*)(Bj + (size_t)row * 256) + cb,
            (char*)lB[buf] + chunk * 1024);
    }
  };

  f32x4 acc[4][4] = {};
  f32x4 tmp[4][4] = {};
  stage(0, 0, 0);
  __syncthreads();
  int cur = 0;
  for (int s = 0; s < 16; s++) {
    int jj = s >> 2, kt = s & 3;
    if (s < 15) stage((s + 1) >> 2, (s + 1) & 3, cur ^ 1);   // prefetch next
    bf16x8 afr[2][4];
    #pragma unroll
    for (int kk = 0; kk < 2; kk++)
      #pragma unroll
      for (int mf = 0; mf < 4; mf++)
        afr[kk][mf] = *(const bf16x8*)(qpb + (size_t)(m0 + mf*16 + r) * 256
                                       + kt*64 + kk*32 + hi*8);
    #pragma unroll
    for (int kk = 0; kk < 2; kk++) {
      int kc = kk*32 + hi*8;
      bf16x8 bfr[4];
      #pragma unroll
      for (int nf = 0; nf < 4; nf++) {
        int bn = w*64 + nf*16 + r;
        bfr[nf] = *(const bf16x8*)((const char*)lB[cur] + bn*128 + ((kc*2) ^ ((bn&7)<<4)));
      }
      #pragma unroll
      for (int mf = 0; mf < 4; mf++)
        #pragma unroll
        for (int nf = 0; nf < 4; nf++)
          tmp[mf][nf] = __builtin_amdgcn_mfma_f32_16x16x32_bf16(afr[kk][mf], bfr[nf], tmp[mf][nf], 0, 0, 0);
    }
    if (kt == 3) {                    // per-j epilogue: acc += qp[i,j] * T_j
      int jcol = jbase + jj;
      #pragma unroll
      for (int mf = 0; mf < 4; mf++)
        #pragma unroll
        for (int qq = 0; qq < 4; qq++) {
          float sv = qpf[(size_t)(m0 + mf*16 + hi*4 + qq) * DM + jcol];
          #pragma unroll
          for (int nf = 0; nf < 4; nf++) acc[mf][nf][qq] += sv * tmp[mf][nf][qq];
        }
      #pragma unroll
      for (int mf = 0; mf < 4; mf++)
        #pragma unroll
        for (int nf = 0; nf < 4; nf++) tmp[mf][nf] = (f32x4){0.f,0.f,0.f,0.f};
    }
    __syncthreads();                  // drains prefetch vmcnt AFTER compute
    cur ^= 1;
  }
  float* dst = af8 + (size_t)jsplit * (NH * SEQ * DM);
  #pragma unroll
  for (int mf = 0; mf < 4; mf++)
    #pragma unroll
    for (int nf = 0; nf < 4; nf++)
      #pragma unroll
      for (int qq = 0; qq < 4; qq++)
        dst[((size_t)head * SEQ + m0 + mf*16 + hi*4 + qq) * DM + w*64 + nf*16 + r]
            = acc[mf][nf][qq];
}

// ---------------------------------------------------------------------------
// kfold: abf[x] = bf16( sum_{s<8} af8[s][x] )
__global__ __launch_bounds__(256) void kfold(const float* __restrict__ af8,
                                             unsigned short* __restrict__ abf) {
  const size_t S = (size_t)NH * SEQ * DM;
  size_t idx = ((size_t)blockIdx.x * 256 + threadIdx.x) * 8;
  float4 s0 = {0,0,0,0}, s1 = {0,0,0,0};
  #pragma unroll
  for (int p = 0; p < 8; p++) {
    float4 a = *(const float4*)(af8 + p * S + idx);
    float4 b = *(const float4*)(af8 + p * S + idx + 4);
    s0.x+=a.x; s0.y+=a.y; s0.z+=a.z; s0.w+=a.w;
    s1.x+=b.x; s1.y+=b.y; s1.z+=b.z; s1.w+=b.w;
  }
  *(s16x8*)(abf + idx) = cvt8(s0, s1);
}

// ---------------------------------------------------------------------------
// ko5: 2-phase pipelined per-j GEMM + w-dot epilogue. Per block: for 4 j's,
// U_j = qpb[m0:+64] @ Wvb_j^T over 4 kt steps; epilogue out[i,j] += sum_b
// U_j[i,b]*w[head,i,b] (w read from L2-hot global; shfl-reduce over r).
// grid 512, 256 thr, 64 KiB LDS, 2 blk/CU.
__global__ __launch_bounds__(256, 2) void ko5(const unsigned short* __restrict__ Wvb,
                                              const unsigned short* __restrict__ qpb,
                                              const unsigned short* __restrict__ wbf,
                                              float* __restrict__ out) {
  __shared__ __align__(16) unsigned short lB[2][256 * 64];
  int bid = blockIdx.x;
  int head = bid & 7, rest = bid >> 3;
  int jsplit = rest >> 3, itile = rest & 7;
  int m0 = itile * 64;
  int t = threadIdx.x, w = t >> 6, lane = t & 63;
  int r = lane & 15, hi = lane >> 4;
  const int jbase = head * 32 + jsplit * 4;

  auto stage = [&](int jj, int kt, int buf) {
    const unsigned short* Bj = Wvb + (size_t)(jbase + jj) * 65536 + kt * 64;
    #pragma unroll
    for (int it = 0; it < 8; it++) {
      int chunk = w * 8 + it;
      int row = chunk * 8 + (lane >> 3);
      int cb = ((lane & 7) * 16) ^ ((row & 7) << 4);
      gll16((const char*)(Bj + (size_t)row * 256) + cb,
            (char*)lB[buf] + chunk * 1024);
    }
  };

  f32x4 tmp[4][4] = {};
  stage(0, 0, 0);
  __syncthreads();
  int cur = 0;
  for (int s = 0; s < 16; s++) {
    int jj = s >> 2, kt = s & 3;
    if (s < 15) stage((s + 1) >> 2, (s + 1) & 3, cur ^ 1);
    bf16x8 afr[2][4];
    #pragma unroll
    for (int kk = 0; kk < 2; kk++)
      #pragma unroll
      for (int mf = 0; mf < 4; mf++)
        afr[kk][mf] = *(const bf16x8*)(qpb + (size_t)(m0 + mf*16 + r) * 256
                                       + kt*64 + kk*32 + hi*8);
    #pragma unroll
    for (int kk = 0; kk < 2; kk++) {
      int kc = kk*32 + hi*8;
      bf16x8 bfr[4];
      #pragma unroll
      for (int nf = 0; nf < 4; nf++) {
        int bn = w*64 + nf*16 + r;
        bfr[nf] = *(const bf16x8*)((const char*)lB[cur] + bn*128 + ((kc*2) ^ ((bn&7)<<4)));
      }
      #pragma unroll
      for (int mf = 0; mf < 4; mf++)
        #pragma unroll
        for (int nf = 0; nf < 4; nf++)
          tmp[mf][nf] = __builtin_amdgcn_mfma_f32_16x16x32_bf16(afr[kk][mf], bfr[nf], tmp[mf][nf], 0, 0, 0);
    }
    if (kt == 3) {                    // epilogue: dot U_j vs w over b-cols
      int jcol = jbase + jj;
      #pragma unroll
      for (int mf = 0; mf < 4; mf++)
        #pragma unroll
        for (int qq = 0; qq < 4; qq++) {
          int rloc = mf*16 + hi*4 + qq;
          const unsigned short* wrow = wbf + ((size_t)head * SEQ + m0 + rloc) * DM + w*64;
          float pp = 0.f;
          #pragma unroll
          for (int nf = 0; nf < 4; nf++)
            pp += tmp[mf][nf][qq] * bf2f(wrow[nf*16 + r]);
          pp += __shfl_xor(pp, 1);
          pp += __shfl_xor(pp, 2);
          pp += __shfl_xor(pp, 4);
          pp += __shfl_xor(pp, 8);
          if (r == 0) atomicAdd(&out[(size_t)(m0 + rloc) * DM + jcol], pp);
        }
      #pragma unroll
      for (int mf = 0; mf < 4; mf++)
        #pragma unroll
        for (int nf = 0; nf < 4; nf++) tmp[mf][nf] = (f32x4){0.f,0.f,0.f,0.f};
    }
    __syncthreads();
    cur ^= 1;
  }
}

// ---------------------------------------------------------------------------
// Small 64x64-tile NT GEMM: C[M,N] = A[M,K] * B[N,K]^T, 4 waves (2x2)
template<int CONVA, int OUTBF>
__global__ __launch_bounds__(256) void gemm_small(const void* __restrict__ Ap,
                                                  const unsigned short* __restrict__ B,
                                                  void* __restrict__ Cp,
                                                  int M, int N, int K, int nMtiles) {
  __shared__ __align__(16) unsigned short lA[64 * 72];
  __shared__ __align__(16) unsigned short lB[64 * 72];
  int bid = blockIdx.x;
  int mtile = bid % nMtiles, ntile = bid / nMtiles;
  int m0 = mtile * 64, n0 = ntile * 64;
  int t = threadIdx.x, w = t >> 6, lane = t & 63;
  int wr = w >> 1, wcc = w & 1;
  f32x4 acc[2][2] = {};
  for (int kt = 0; kt < K; kt += 64) {
    __syncthreads();
    #pragma unroll
    for (int rep = 0; rep < 2; rep++) {
      int sc = rep * 256 + t;
      int row = sc >> 3, c8 = sc & 7;
      if (CONVA) {
        const float* src = (const float*)Ap + (size_t)(m0 + row) * K + kt + c8 * 8;
        float4 u0 = *(const float4*)src, u1 = *(const float4*)(src + 4);
        *(s16x8*)&lA[row * 72 + c8 * 8] = cvt8(u0, u1);
      } else {
        *(s16x8*)&lA[row * 72 + c8 * 8] =
            *(const s16x8*)((const unsigned short*)Ap + (size_t)(m0 + row) * K + kt + c8 * 8);
      }
      *(s16x8*)&lB[row * 72 + c8 * 8] = *(const s16x8*)(B + (size_t)(n0 + row) * K + kt + c8 * 8);
    }
    __syncthreads();
    #pragma unroll
    for (int kk = 0; kk < 2; kk++) {
      int r = lane & 15, kc = kk * 32 + (lane >> 4) * 8;
      bf16x8 afr[2], bfr[2];
      #pragma unroll
      for (int mf = 0; mf < 2; mf++) afr[mf] = *(const bf16x8*)&lA[(wr*32 + mf*16 + r) * 72 + kc];
      #pragma unroll
      for (int nf = 0; nf < 2; nf++) bfr[nf] = *(const bf16x8*)&lB[(wcc*32 + nf*16 + r) * 72 + kc];
      #pragma unroll
      for (int mf = 0; mf < 2; mf++)
        #pragma unroll
        for (int nf = 0; nf < 2; nf++)
          acc[mf][nf] = __builtin_amdgcn_mfma_f32_16x16x32_bf16(afr[mf], bfr[nf], acc[mf][nf], 0, 0, 0);
    }
  }
  int cr = (lane >> 4) * 4, cc = lane & 15;
  #pragma unroll
  for (int mf = 0; mf < 2; mf++)
    #pragma unroll
    for (int nf = 0; nf < 2; nf++)
      #pragma unroll
      for (int qq = 0; qq < 4; qq++) {
        int row = m0 + wr*32 + mf*16 + cr + qq;
        int col = n0 + wcc*32 + nf*16 + cc;
        float vv = acc[mf][nf][qq];
        if (OUTBF) ((unsigned short*)Cp)[(size_t)row * N + col] = f2bf(vv);
        else       ((float*)Cp)[(size_t)row * N + col] = vv;
      }
}

// ---------------------------------------------------------------------------
// softmax over rows of logits[n*512+i][l], causal l<=i, scale 1/sqrt(512)
__global__ __launch_bounds__(256) void k4b_softmax(const float* __restrict__ logits,
                                                   unsigned short* __restrict__ probs) {
  __shared__ float red[4];
  __shared__ float red2[4];
  int m = blockIdx.x, t = threadIdx.x;
  int i = m & (SEQ - 1);
  const float scale = 0.04419417382415922f;   // 1/sqrt(512)
  const float NEG = -1e30f;
  float v0 = (t       <= i) ? logits[(size_t)m * SEQ + t      ] * scale : NEG;
  float v1 = (t + 256 <= i) ? logits[(size_t)m * SEQ + t + 256] * scale : NEG;
  float mx = fmaxf(v0, v1);
  #pragma unroll
  for (int off = 32; off; off >>= 1) mx = fmaxf(mx, __shfl_xor(mx, off));
  int w = t >> 6, lane = t & 63;
  if (lane == 0) red[w] = mx;
  __syncthreads();
  mx = fmaxf(fmaxf(red[0], red[1]), fmaxf(red[2], red[3]));
  float e0 = (t       <= i) ? __expf(v0 - mx) : 0.f;
  float e1 = (t + 256 <= i) ? __expf(v1 - mx) : 0.f;
  float s = e0 + e1;
  #pragma unroll
  for (int off = 32; off; off >>= 1) s += __shfl_xor(s, off);
  if (lane == 0) red2[w] = s;
  __syncthreads();
  s = red2[0] + red2[1] + red2[2] + red2[3];
  float inv = 1.f / s;
  probs[(size_t)m * SEQ + t]       = f2bf(e0 * inv);
  probs[(size_t)m * SEQ + t + 256] = f2bf(e1 * inv);
}

// ---------------------------------------------------------------------------
extern "C" void kernel_launch(void* const* d_in, const int* in_sizes, int n_in,
                              void* d_out, int out_size, void* d_ws, size_t ws_size,
                              hipStream_t stream) {
  (void)in_sizes; (void)n_in; (void)out_size; (void)ws_size;
  const float* q  = (const float*)d_in[0];
  const float* k  = (const float*)d_in[1];
  const float* v  = (const float*)d_in[2];
  const float* Wq = (const float*)d_in[3];
  const float* Wk = (const float*)d_in[4];
  const float* Wv = (const float*)d_in[5];
  float* out = (float*)d_out;

  char* ws = (char*)d_ws;
  size_t off = 0;
  auto alloc = [&](size_t bytes) -> void* {
    void* p = ws + off; off += (bytes + 255) & ~(size_t)255; return p;
  };
  float*          qpf    = (float*)         alloc((size_t)SEQ * DM * 4);
  unsigned short* qpb    = (unsigned short*)alloc((size_t)SEQ * DM * 2);
  unsigned short* kbf    = (unsigned short*)alloc((size_t)SEQ * DM * 2);
  unsigned short* vT     = (unsigned short*)alloc((size_t)DM * SEQ * 2);
  unsigned short* Wkb    = (unsigned short*)alloc((size_t)DM * DM * DM * 2);  // 32 MB
  unsigned short* Wvb    = (unsigned short*)alloc((size_t)DM * DM * DM * 2);  // 32 MB
  float*          af8    = (float*)         alloc((size_t)8 * NH * SEQ * DM * 4); // 32 MB
  unsigned short* abf    = (unsigned short*)alloc((size_t)NH * SEQ * DM * 2); // 2 MB
  float*          logits = (float*)         alloc((size_t)NH * SEQ * SEQ * 4);
  unsigned short* probs  = (unsigned short*)alloc((size_t)NH * SEQ * SEQ * 2);
  unsigned short* wbf    = (unsigned short*)alloc((size_t)NH * SEQ * DM * 2);

  hipMemsetAsync(out, 0, (size_t)SEQ * DM * 4, stream);

  kconv<<<2048, 256, 0, stream>>>(Wk, Wkb);
  kconv<<<2048, 256, 0, stream>>>(Wv, Wvb);
  k0_convert<<<64, 256, 0, stream>>>(k, v, kbf, vT);
  k1_qproj<<<SEQ, 256, 0, stream>>>(q, Wq, qpf, qpb);
  // a-partials: pipelined per-j GEMM (17.2 GFLOP), disjoint stores
  ka5<<<512, 256, 0, stream>>>(Wkb, qpb, qpf, af8);
  kfold<<<512, 256, 0, stream>>>(af8, abf);
  // logits = a @ kbf^T : M=4096, N=512, K=256
  gemm_small<0,0><<<512, 256, 0, stream>>>((const void*)abf, kbf, (void*)logits, NH*SEQ, SEQ, DM, 64);
  k4b_softmax<<<NH*SEQ, 256, 0, stream>>>(logits, probs);
  // w = probs @ v : M=4096, N=256, K=512 (B = vT)
  gemm_small<0,1><<<256, 256, 0, stream>>>((const void*)probs, vT, (void*)wbf, NH*SEQ, DM, SEQ, 64);
  // out: pipelined per-j GEMM + dot-vs-w epilogue (17.2 GFLOP)
  ko5<<<512, 256, 0, stream>>>(Wvb, qpb, wbf, out);
}